// Round 1
// baseline (264.000 us; speedup 1.0000x reference)
//
#include <hip/hip_runtime.h>

// Problem constants (Graphormer node feature + SAGE conv)
#define G_   64
#define NODES_ 511
#define NN_  512          // NODES + 1 (graph token row 0)
#define H_   768
#define E_   4096
#define NTYPE 5           // graph_emb + node_emb[0..3]

// ---------------------------------------------------------------------------
// Kernel 1: per-(graph, dst-node) typed in-degree counts.
// cnt[g][d][t] = #edges into d whose src row has embedding type t.
// deg[g][d] = sum_t cnt — recovered in the output kernel.
// ---------------------------------------------------------------------------
__global__ void count_kernel(const int* __restrict__ edges,   // (G, 2, E)
                             const int* __restrict__ nodes,   // (G, NODES)
                             int* __restrict__ cnt)           // (G, NN, 5)
{
    int idx = blockIdx.x * blockDim.x + threadIdx.x;          // G*E threads
    int g = idx >> 12;                                        // E = 4096
    int e = idx & (E_ - 1);
    const int* eg = edges + (size_t)g * 2 * E_;
    int src = eg[e];
    int dst = eg[E_ + e];
    int type = (src == 0) ? 0 : (nodes[g * NODES_ + src - 1] + 1);
    atomicAdd(&cnt[((g * NN_ + dst) * NTYPE) + type], 1);
}

// ---------------------------------------------------------------------------
// Kernel 2: tiny projections of the 5 distinct embedding rows.
// P_l[t] = emb_t @ W_l^T ;  P_r[t] = emb_t @ W_r^T + b_l  (b_l folded in)
// ---------------------------------------------------------------------------
__global__ void proj_kernel(const float* __restrict__ node_emb,  // (4, H)
                            const float* __restrict__ graph_emb, // (1, H)
                            const float* __restrict__ W_l,       // (H, H)
                            const float* __restrict__ b_l,       // (H,)
                            const float* __restrict__ W_r,       // (H, H)
                            float* __restrict__ P_l,             // (5, H)
                            float* __restrict__ P_r)             // (5, H)
{
    int idx = blockIdx.x * blockDim.x + threadIdx.x;             // 2*5*H threads
    int m = idx / (NTYPE * H_);      // 0 -> W_l, 1 -> W_r
    int r = idx % (NTYPE * H_);
    int t = r / H_;
    int j = r % H_;
    const float* emb = (t == 0) ? graph_emb : (node_emb + (size_t)(t - 1) * H_);
    const float* W   = ((m == 0) ? W_l : W_r) + (size_t)j * H_;
    float acc = 0.0f;
    for (int k = 0; k < H_; k += 4) {
        float4 wv = *(const float4*)(W + k);
        float4 ev = *(const float4*)(emb + k);
        acc += wv.x * ev.x + wv.y * ev.y + wv.z * ev.z + wv.w * ev.w;
    }
    if (m == 0) P_l[t * H_ + j] = acc;
    else        P_r[t * H_ + j] = acc + b_l[j];
}

// ---------------------------------------------------------------------------
// Kernel 3: write both outputs. One thread per float4 of each (g,n) row.
//  gnf[g,n] = emb_{type(g,n)}
//  gef[g,n] = (sum_t cnt[g,n,t] * P_l[t]) / max(deg,1) + P_r[type(g,n)]
// ---------------------------------------------------------------------------
__global__ void out_kernel(const int* __restrict__ nodes,     // (G, NODES)
                           const int* __restrict__ cnt,       // (G, NN, 5)
                           const float* __restrict__ node_emb,
                           const float* __restrict__ graph_emb,
                           const float* __restrict__ P_l,
                           const float* __restrict__ P_r,
                           float* __restrict__ gnf,           // (G, NN, H)
                           float* __restrict__ gef)           // (G, NN, H)
{
    int tid = blockIdx.x * blockDim.x + threadIdx.x;   // G*NN*(H/4) threads
    int row = tid / (H_ / 4);                          // (g*NN + n)
    int j4  = tid % (H_ / 4);                          // float4 index in row
    int g = row >> 9;                                  // NN = 512
    int n = row & (NN_ - 1);

    int type = (n == 0) ? 0 : (nodes[g * NODES_ + n - 1] + 1);

    const int* c = cnt + (size_t)row * NTYPE;
    float c0 = (float)c[0], c1 = (float)c[1], c2 = (float)c[2],
          c3 = (float)c[3], c4 = (float)c[4];
    float deg = c0 + c1 + c2 + c3 + c4;
    float inv = 1.0f / fmaxf(deg, 1.0f);

    int h = j4 * 4;
    float4 p0 = *(const float4*)(P_l + 0 * H_ + h);
    float4 p1 = *(const float4*)(P_l + 1 * H_ + h);
    float4 p2 = *(const float4*)(P_l + 2 * H_ + h);
    float4 p3 = *(const float4*)(P_l + 3 * H_ + h);
    float4 p4 = *(const float4*)(P_l + 4 * H_ + h);
    float4 pr = *(const float4*)(P_r + (size_t)type * H_ + h);

    float4 o;
    o.x = (c0 * p0.x + c1 * p1.x + c2 * p2.x + c3 * p3.x + c4 * p4.x) * inv + pr.x;
    o.y = (c0 * p0.y + c1 * p1.y + c2 * p2.y + c3 * p3.y + c4 * p4.y) * inv + pr.y;
    o.z = (c0 * p0.z + c1 * p1.z + c2 * p2.z + c3 * p3.z + c4 * p4.z) * inv + pr.z;
    o.w = (c0 * p0.w + c1 * p1.w + c2 * p2.w + c3 * p3.w + c4 * p4.w) * inv + pr.w;

    const float* emb = (type == 0) ? graph_emb : (node_emb + (size_t)(type - 1) * H_);
    float4 ev = *(const float4*)(emb + h);

    size_t off = (size_t)row * H_ + h;
    *(float4*)(gnf + off) = ev;
    *(float4*)(gef + off) = o;
}

// ---------------------------------------------------------------------------
extern "C" void kernel_launch(void* const* d_in, const int* in_sizes, int n_in,
                              void* d_out, int out_size, void* d_ws, size_t ws_size,
                              hipStream_t stream)
{
    const int*   input_nodes = (const int*)d_in[0];   // (G, NODES) int32
    const int*   input_edges = (const int*)d_in[1];   // (G, 2, E)  int32
    const float* node_emb    = (const float*)d_in[2]; // (4, H)
    const float* graph_emb   = (const float*)d_in[3]; // (1, H)
    const float* W_l         = (const float*)d_in[4]; // (H, H)
    const float* b_l         = (const float*)d_in[5]; // (H,)
    const float* W_r         = (const float*)d_in[6]; // (H, H)

    float* gnf = (float*)d_out;                        // output 0: (G, NN, H)
    float* gef = gnf + (size_t)G_ * NN_ * H_;          // output 1: (G, NN, H)

    int*   cnt = (int*)d_ws;                                    // G*NN*5 ints = 2.62 MB
    size_t cnt_bytes = (size_t)G_ * NN_ * NTYPE * sizeof(int);
    float* P_l = (float*)((char*)d_ws + cnt_bytes);             // 5*H floats
    float* P_r = P_l + NTYPE * H_;                              // 5*H floats

    hipMemsetAsync(cnt, 0, cnt_bytes, stream);

    // G*E = 262144 = 1024 * 256
    count_kernel<<<(G_ * E_) / 256, 256, 0, stream>>>(input_edges, input_nodes, cnt);

    // 2*5*H = 7680 = 30 * 256
    proj_kernel<<<(2 * NTYPE * H_) / 256, 256, 0, stream>>>(
        node_emb, graph_emb, W_l, b_l, W_r, P_l, P_r);

    // G*NN*(H/4) = 6291456 = 24576 * 256
    out_kernel<<<(G_ * NN_ * (H_ / 4)) / 256, 256, 0, stream>>>(
        input_nodes, cnt, node_emb, graph_emb, P_l, P_r, gnf, gef);
}

// Round 3
// 233.105 us; speedup vs baseline: 1.1325x; 1.1325x over previous
//
#include <hip/hip_runtime.h>

// Problem constants (Graphormer node feature + SAGE conv)
#define G_   64
#define NODES_ 511
#define NN_  512          // NODES + 1 (graph token row 0)
#define H_   768
#define E_   4096
#define NTYPE 5           // graph_emb + node_emb[0..3]

typedef float f32x4 __attribute__((ext_vector_type(4)));  // clang vector: OK for nontemporal builtins

// ---------------------------------------------------------------------------
// Kernel 1: per-(graph, dst-node) typed in-degree counts.
// cnt[g][d][t] = #edges into d whose src row has embedding type t.
// ---------------------------------------------------------------------------
__global__ void count_kernel(const int* __restrict__ edges,   // (G, 2, E)
                             const int* __restrict__ nodes,   // (G, NODES)
                             int* __restrict__ cnt)           // (G, NN, 5)
{
    int idx = blockIdx.x * blockDim.x + threadIdx.x;          // G*E threads
    int g = idx >> 12;                                        // E = 4096
    int e = idx & (E_ - 1);
    const int* eg = edges + (size_t)g * 2 * E_;
    int src = eg[e];
    int dst = eg[E_ + e];
    int type = (src == 0) ? 0 : (nodes[g * NODES_ + src - 1] + 1);
    atomicAdd(&cnt[((g * NN_ + dst) * NTYPE) + type], 1);
}

// ---------------------------------------------------------------------------
// Kernel 2: tiny projections of the 5 distinct embedding rows.
// P_l[t] = emb_t @ W_l^T ;  P_r[t] = emb_t @ W_r^T + b_l  (b_l folded in)
// Wave-per-output: 2*5*768 = 7680 waves. Each lane reads 3 float4s
// (coalesced across the W row), then 6-step butterfly shuffle reduce.
// ---------------------------------------------------------------------------
__global__ void proj_kernel(const float* __restrict__ node_emb,  // (4, H)
                            const float* __restrict__ graph_emb, // (1, H)
                            const float* __restrict__ W_l,       // (H, H)
                            const float* __restrict__ b_l,       // (H,)
                            const float* __restrict__ W_r,       // (H, H)
                            float* __restrict__ P_l,             // (5, H)
                            float* __restrict__ P_r)             // (5, H)
{
    int wave = (blockIdx.x * blockDim.x + threadIdx.x) >> 6;     // 7680 waves
    int lane = threadIdx.x & 63;
    int m = wave / (NTYPE * H_);     // 0 -> W_l, 1 -> W_r
    int r = wave % (NTYPE * H_);
    int t = r / H_;
    int j = r % H_;
    const float* emb = (t == 0) ? graph_emb : (node_emb + (size_t)(t - 1) * H_);
    const float* W   = ((m == 0) ? W_l : W_r) + (size_t)j * H_;

    float a0, a1, a2;
    {
        int k0 = lane * 4;
        f32x4 w0 = *(const f32x4*)(W + k0);
        f32x4 e0 = *(const f32x4*)(emb + k0);
        f32x4 w1 = *(const f32x4*)(W + k0 + 256);
        f32x4 e1 = *(const f32x4*)(emb + k0 + 256);
        f32x4 w2 = *(const f32x4*)(W + k0 + 512);
        f32x4 e2 = *(const f32x4*)(emb + k0 + 512);
        a0 = w0.x * e0.x + w0.y * e0.y + w0.z * e0.z + w0.w * e0.w;
        a1 = w1.x * e1.x + w1.y * e1.y + w1.z * e1.z + w1.w * e1.w;
        a2 = w2.x * e2.x + w2.y * e2.y + w2.z * e2.z + w2.w * e2.w;
    }
    float acc = a0 + a1 + a2;
    #pragma unroll
    for (int off = 32; off; off >>= 1)
        acc += __shfl_xor(acc, off, 64);

    if (lane == 0) {
        if (m == 0) P_l[t * H_ + j] = acc;
        else        P_r[t * H_ + j] = acc + b_l[j];
    }
}

// ---------------------------------------------------------------------------
// Kernel 3: write both outputs. One thread per float4 of each (g,n) row.
//  gnf[g,n] = emb_{type(g,n)}
//  gef[g,n] = (sum_t cnt[g,n,t] * P_l[t]) / max(deg,1) + P_r[type(g,n)]
// Streaming 201 MB of writes -> nontemporal stores (no reuse, > L2).
// ---------------------------------------------------------------------------
__global__ void out_kernel(const int* __restrict__ nodes,     // (G, NODES)
                           const int* __restrict__ cnt,       // (G, NN, 5)
                           const float* __restrict__ node_emb,
                           const float* __restrict__ graph_emb,
                           const float* __restrict__ P_l,
                           const float* __restrict__ P_r,
                           float* __restrict__ gnf,           // (G, NN, H)
                           float* __restrict__ gef)           // (G, NN, H)
{
    int tid = blockIdx.x * blockDim.x + threadIdx.x;   // G*NN*(H/4) threads
    int row = tid / (H_ / 4);                          // (g*NN + n)
    int j4  = tid % (H_ / 4);                          // float4 index in row
    int g = row >> 9;                                  // NN = 512
    int n = row & (NN_ - 1);

    int type = (n == 0) ? 0 : (nodes[g * NODES_ + n - 1] + 1);

    const int* c = cnt + (size_t)row * NTYPE;
    float c0 = (float)c[0], c1 = (float)c[1], c2 = (float)c[2],
          c3 = (float)c[3], c4 = (float)c[4];
    float deg = c0 + c1 + c2 + c3 + c4;
    float inv = 1.0f / fmaxf(deg, 1.0f);

    int h = j4 * 4;
    f32x4 p0 = *(const f32x4*)(P_l + 0 * H_ + h);
    f32x4 p1 = *(const f32x4*)(P_l + 1 * H_ + h);
    f32x4 p2 = *(const f32x4*)(P_l + 2 * H_ + h);
    f32x4 p3 = *(const f32x4*)(P_l + 3 * H_ + h);
    f32x4 p4 = *(const f32x4*)(P_l + 4 * H_ + h);
    f32x4 pr = *(const f32x4*)(P_r + (size_t)type * H_ + h);

    f32x4 o = (c0 * p0 + c1 * p1 + c2 * p2 + c3 * p3 + c4 * p4) * inv + pr;

    const float* emb = (type == 0) ? graph_emb : (node_emb + (size_t)(type - 1) * H_);
    f32x4 ev = *(const f32x4*)(emb + h);

    size_t off = (size_t)row * H_ + h;
    __builtin_nontemporal_store(ev, (f32x4*)(gnf + off));
    __builtin_nontemporal_store(o,  (f32x4*)(gef + off));
}

// ---------------------------------------------------------------------------
extern "C" void kernel_launch(void* const* d_in, const int* in_sizes, int n_in,
                              void* d_out, int out_size, void* d_ws, size_t ws_size,
                              hipStream_t stream)
{
    const int*   input_nodes = (const int*)d_in[0];   // (G, NODES) int32
    const int*   input_edges = (const int*)d_in[1];   // (G, 2, E)  int32
    const float* node_emb    = (const float*)d_in[2]; // (4, H)
    const float* graph_emb   = (const float*)d_in[3]; // (1, H)
    const float* W_l         = (const float*)d_in[4]; // (H, H)
    const float* b_l         = (const float*)d_in[5]; // (H,)
    const float* W_r         = (const float*)d_in[6]; // (H, H)

    float* gnf = (float*)d_out;                        // output 0: (G, NN, H)
    float* gef = gnf + (size_t)G_ * NN_ * H_;          // output 1: (G, NN, H)

    int*   cnt = (int*)d_ws;                                    // G*NN*5 ints = 2.62 MB
    size_t cnt_bytes = (size_t)G_ * NN_ * NTYPE * sizeof(int);
    float* P_l = (float*)((char*)d_ws + cnt_bytes);             // 5*H floats
    float* P_r = P_l + NTYPE * H_;                              // 5*H floats

    (void)hipMemsetAsync(cnt, 0, cnt_bytes, stream);

    // G*E = 262144 = 1024 * 256
    count_kernel<<<(G_ * E_) / 256, 256, 0, stream>>>(input_edges, input_nodes, cnt);

    // 7680 waves, 4 waves per 256-thread block -> 1920 blocks
    proj_kernel<<<(2 * NTYPE * H_) / 4, 256, 0, stream>>>(
        node_emb, graph_emb, W_l, b_l, W_r, P_l, P_r);

    // G*NN*(H/4) = 6291456 = 24576 * 256
    out_kernel<<<(G_ * NN_ * (H_ / 4)) / 256, 256, 0, stream>>>(
        input_nodes, cnt, node_emb, graph_emb, P_l, P_r, gnf, gef);
}

// Round 4
// 227.076 us; speedup vs baseline: 1.1626x; 1.0265x over previous
//
#include <hip/hip_runtime.h>

// Problem constants (Graphormer node feature + SAGE conv)
#define G_   64
#define NODES_ 511
#define NN_  512          // NODES + 1 (graph token row 0)
#define H_   768
#define E_   4096
#define NTYPE 5           // graph_emb + node_emb[0..3]

typedef float f32x4 __attribute__((ext_vector_type(4)));  // clang vector: OK for nontemporal builtins

// ---------------------------------------------------------------------------
// Kernel 1: per-(graph, dst-node) typed in-degree counts via LDS histogram.
// One block per graph (512 threads, 8 edges each). cnt[g][d][t] built with
// ds_add (LDS atomics, ~uniform bank spread), then written out coalesced.
// No global atomics, no memset needed.
// ---------------------------------------------------------------------------
__global__ __launch_bounds__(512)
void count_kernel(const int* __restrict__ edges,   // (G, 2, E)
                  const int* __restrict__ nodes,   // (G, NODES)
                  int* __restrict__ cnt)           // (G, NN, 5)
{
    __shared__ int hist[NN_ * NTYPE];              // 10 KB
    int g = blockIdx.x;
    int t = threadIdx.x;

    #pragma unroll
    for (int i = 0; i < NN_ * NTYPE / 512; ++i)    // 5 per thread
        hist[t + i * 512] = 0;
    __syncthreads();

    const int* eg = edges + (size_t)g * 2 * E_;
    const int* ng = nodes + (size_t)g * NODES_;
    #pragma unroll
    for (int i = 0; i < E_ / 512; ++i) {           // 8 edges per thread
        int e = t + i * 512;
        int src = eg[e];
        int dst = eg[E_ + e];
        int type = (src == 0) ? 0 : (ng[src - 1] + 1);
        atomicAdd(&hist[dst * NTYPE + type], 1);
    }
    __syncthreads();

    int* cg = cnt + (size_t)g * NN_ * NTYPE;
    #pragma unroll
    for (int i = 0; i < NN_ * NTYPE / 512; ++i)    // coalesced 10 KB store
        cg[t + i * 512] = hist[t + i * 512];
}

// ---------------------------------------------------------------------------
// Kernel 2: tiny projections of the 5 distinct embedding rows.
// P_l[t] = emb_t @ W_l^T ;  P_r[t] = emb_t @ W_r^T + b_l  (b_l folded in)
// Wave-per-output: 2*5*768 = 7680 waves; 6-step butterfly shuffle reduce.
// ---------------------------------------------------------------------------
__global__ void proj_kernel(const float* __restrict__ node_emb,  // (4, H)
                            const float* __restrict__ graph_emb, // (1, H)
                            const float* __restrict__ W_l,       // (H, H)
                            const float* __restrict__ b_l,       // (H,)
                            const float* __restrict__ W_r,       // (H, H)
                            float* __restrict__ P_l,             // (5, H)
                            float* __restrict__ P_r)             // (5, H)
{
    int wave = (blockIdx.x * blockDim.x + threadIdx.x) >> 6;     // 7680 waves
    int lane = threadIdx.x & 63;
    int m = wave / (NTYPE * H_);     // 0 -> W_l, 1 -> W_r
    int r = wave % (NTYPE * H_);
    int t = r / H_;
    int j = r % H_;
    const float* emb = (t == 0) ? graph_emb : (node_emb + (size_t)(t - 1) * H_);
    const float* W   = ((m == 0) ? W_l : W_r) + (size_t)j * H_;

    float a0, a1, a2;
    {
        int k0 = lane * 4;
        f32x4 w0 = *(const f32x4*)(W + k0);
        f32x4 e0 = *(const f32x4*)(emb + k0);
        f32x4 w1 = *(const f32x4*)(W + k0 + 256);
        f32x4 e1 = *(const f32x4*)(emb + k0 + 256);
        f32x4 w2 = *(const f32x4*)(W + k0 + 512);
        f32x4 e2 = *(const f32x4*)(emb + k0 + 512);
        a0 = w0.x * e0.x + w0.y * e0.y + w0.z * e0.z + w0.w * e0.w;
        a1 = w1.x * e1.x + w1.y * e1.y + w1.z * e1.z + w1.w * e1.w;
        a2 = w2.x * e2.x + w2.y * e2.y + w2.z * e2.z + w2.w * e2.w;
    }
    float acc = a0 + a1 + a2;
    #pragma unroll
    for (int off = 32; off; off >>= 1)
        acc += __shfl_xor(acc, off, 64);

    if (lane == 0) {
        if (m == 0) P_l[t * H_ + j] = acc;
        else        P_r[t * H_ + j] = acc + b_l[j];
    }
}

// ---------------------------------------------------------------------------
// Kernel 3: write both outputs. One thread per float4 of each (g,n) row.
//  gnf[g,n] = emb_{type(g,n)}
//  gef[g,n] = (sum_t cnt[g,n,t] * P_l[t]) / max(deg,1) + P_r[type(g,n)]
// Streaming 201 MB of writes -> nontemporal stores (no reuse, > L2).
// ---------------------------------------------------------------------------
__global__ void out_kernel(const int* __restrict__ nodes,     // (G, NODES)
                           const int* __restrict__ cnt,       // (G, NN, 5)
                           const float* __restrict__ node_emb,
                           const float* __restrict__ graph_emb,
                           const float* __restrict__ P_l,
                           const float* __restrict__ P_r,
                           float* __restrict__ gnf,           // (G, NN, H)
                           float* __restrict__ gef)           // (G, NN, H)
{
    int tid = blockIdx.x * blockDim.x + threadIdx.x;   // G*NN*(H/4) threads
    int row = tid / (H_ / 4);                          // (g*NN + n)
    int j4  = tid % (H_ / 4);                          // float4 index in row
    int g = row >> 9;                                  // NN = 512
    int n = row & (NN_ - 1);

    int type = (n == 0) ? 0 : (nodes[g * NODES_ + n - 1] + 1);

    const int* c = cnt + (size_t)row * NTYPE;
    float c0 = (float)c[0], c1 = (float)c[1], c2 = (float)c[2],
          c3 = (float)c[3], c4 = (float)c[4];
    float deg = c0 + c1 + c2 + c3 + c4;
    float inv = 1.0f / fmaxf(deg, 1.0f);

    int h = j4 * 4;
    f32x4 p0 = *(const f32x4*)(P_l + 0 * H_ + h);
    f32x4 p1 = *(const f32x4*)(P_l + 1 * H_ + h);
    f32x4 p2 = *(const f32x4*)(P_l + 2 * H_ + h);
    f32x4 p3 = *(const f32x4*)(P_l + 3 * H_ + h);
    f32x4 p4 = *(const f32x4*)(P_l + 4 * H_ + h);
    f32x4 pr = *(const f32x4*)(P_r + (size_t)type * H_ + h);

    f32x4 o = (c0 * p0 + c1 * p1 + c2 * p2 + c3 * p3 + c4 * p4) * inv + pr;

    const float* emb = (type == 0) ? graph_emb : (node_emb + (size_t)(type - 1) * H_);
    f32x4 ev = *(const f32x4*)(emb + h);

    size_t off = (size_t)row * H_ + h;
    __builtin_nontemporal_store(ev, (f32x4*)(gnf + off));
    __builtin_nontemporal_store(o,  (f32x4*)(gef + off));
}

// ---------------------------------------------------------------------------
extern "C" void kernel_launch(void* const* d_in, const int* in_sizes, int n_in,
                              void* d_out, int out_size, void* d_ws, size_t ws_size,
                              hipStream_t stream)
{
    const int*   input_nodes = (const int*)d_in[0];   // (G, NODES) int32
    const int*   input_edges = (const int*)d_in[1];   // (G, 2, E)  int32
    const float* node_emb    = (const float*)d_in[2]; // (4, H)
    const float* graph_emb   = (const float*)d_in[3]; // (1, H)
    const float* W_l         = (const float*)d_in[4]; // (H, H)
    const float* b_l         = (const float*)d_in[5]; // (H,)
    const float* W_r         = (const float*)d_in[6]; // (H, H)

    float* gnf = (float*)d_out;                        // output 0: (G, NN, H)
    float* gef = gnf + (size_t)G_ * NN_ * H_;          // output 1: (G, NN, H)

    int*   cnt = (int*)d_ws;                                    // G*NN*5 ints = 2.62 MB
    size_t cnt_bytes = (size_t)G_ * NN_ * NTYPE * sizeof(int);
    float* P_l = (float*)((char*)d_ws + cnt_bytes);             // 5*H floats
    float* P_r = P_l + NTYPE * H_;                              // 5*H floats

    // One block per graph; LDS histogram; writes every cnt entry (no memset).
    count_kernel<<<G_, 512, 0, stream>>>(input_edges, input_nodes, cnt);

    // 7680 waves, 4 waves per 256-thread block -> 1920 blocks
    proj_kernel<<<(2 * NTYPE * H_) / 4, 256, 0, stream>>>(
        node_emb, graph_emb, W_l, b_l, W_r, P_l, P_r);

    // G*NN*(H/4) = 6291456 = 24576 * 256
    out_kernel<<<(G_ * NN_ * (H_ / 4)) / 256, 256, 0, stream>>>(
        input_nodes, cnt, node_emb, graph_emb, P_l, P_r, gnf, gef);
}

// Round 5
// 225.305 us; speedup vs baseline: 1.1717x; 1.0079x over previous
//
#include <hip/hip_runtime.h>

// Problem constants (Graphormer node feature + SAGE conv)
#define G_   64
#define NODES_ 511
#define NN_  512          // NODES + 1 (graph token row 0)
#define H_   768
#define E_   4096
#define NTYPE 5           // graph_emb + node_emb[0..3]

typedef float f32x4 __attribute__((ext_vector_type(4)));  // clang vector: OK for nontemporal builtins

// ---------------------------------------------------------------------------
// Kernel 1 (fused prep): blocks 0..63  -> per-graph typed in-degree histogram
//                        blocks 64..1023 -> embedding projections
// The two phases are independent; fusing them overlaps their execution and
// saves one launch. 512 threads/block.
//
// count: cnt[g][d][t] = #edges into d whose src row has embedding type t,
//        built in a 10 KB LDS histogram with ds-atomics, then one coalesced
//        10 KB store (covers every entry -> no memset needed).
// proj:  P_l[t] = emb_t @ W_l^T ; P_r[t] = emb_t @ W_r^T + b_l (b_l folded).
//        Wave-per-output (7680 waves), 6-step butterfly shuffle reduce.
// ---------------------------------------------------------------------------
__global__ __launch_bounds__(512)
void prep_kernel(const int* __restrict__ edges,      // (G, 2, E)
                 const int* __restrict__ nodes,      // (G, NODES)
                 const float* __restrict__ node_emb, // (4, H)
                 const float* __restrict__ graph_emb,// (1, H)
                 const float* __restrict__ W_l,      // (H, H)
                 const float* __restrict__ b_l,      // (H,)
                 const float* __restrict__ W_r,      // (H, H)
                 int* __restrict__ cnt,              // (G, NN, 5)
                 float* __restrict__ P_l,            // (5, H)
                 float* __restrict__ P_r)            // (5, H)
{
    if (blockIdx.x < G_) {
        // ----- count phase: one block per graph -----
        __shared__ int hist[NN_ * NTYPE];              // 10 KB
        int g = blockIdx.x;
        int t = threadIdx.x;

        #pragma unroll
        for (int i = 0; i < NN_ * NTYPE / 512; ++i)    // 5 per thread
            hist[t + i * 512] = 0;
        __syncthreads();

        const int* eg = edges + (size_t)g * 2 * E_;
        const int* ng = nodes + (size_t)g * NODES_;
        #pragma unroll
        for (int i = 0; i < E_ / 512; ++i) {           // 8 edges per thread
            int e = t + i * 512;
            int src = eg[e];
            int dst = eg[E_ + e];
            int type = (src == 0) ? 0 : (ng[src - 1] + 1);
            atomicAdd(&hist[dst * NTYPE + type], 1);
        }
        __syncthreads();

        int* cg = cnt + (size_t)g * NN_ * NTYPE;
        #pragma unroll
        for (int i = 0; i < NN_ * NTYPE / 512; ++i)    // coalesced 10 KB store
            cg[t + i * 512] = hist[t + i * 512];
    } else {
        // ----- proj phase: 960 blocks x 8 waves = 7680 waves -----
        int wave = (blockIdx.x - G_) * 8 + (threadIdx.x >> 6);
        int lane = threadIdx.x & 63;
        int m = wave / (NTYPE * H_);     // 0 -> W_l, 1 -> W_r
        int r = wave % (NTYPE * H_);
        int t = r / H_;
        int j = r % H_;
        const float* emb = (t == 0) ? graph_emb : (node_emb + (size_t)(t - 1) * H_);
        const float* W   = ((m == 0) ? W_l : W_r) + (size_t)j * H_;

        float a0, a1, a2;
        {
            int k0 = lane * 4;
            f32x4 w0 = *(const f32x4*)(W + k0);
            f32x4 e0 = *(const f32x4*)(emb + k0);
            f32x4 w1 = *(const f32x4*)(W + k0 + 256);
            f32x4 e1 = *(const f32x4*)(emb + k0 + 256);
            f32x4 w2 = *(const f32x4*)(W + k0 + 512);
            f32x4 e2 = *(const f32x4*)(emb + k0 + 512);
            a0 = w0.x * e0.x + w0.y * e0.y + w0.z * e0.z + w0.w * e0.w;
            a1 = w1.x * e1.x + w1.y * e1.y + w1.z * e1.z + w1.w * e1.w;
            a2 = w2.x * e2.x + w2.y * e2.y + w2.z * e2.z + w2.w * e2.w;
        }
        float acc = a0 + a1 + a2;
        #pragma unroll
        for (int off = 32; off; off >>= 1)
            acc += __shfl_xor(acc, off, 64);

        if (lane == 0) {
            if (m == 0) P_l[t * H_ + j] = acc;
            else        P_r[t * H_ + j] = acc + b_l[j];
        }
    }
}

// ---------------------------------------------------------------------------
// Kernel 2: write both outputs. One thread per float4 of each (g,n) row.
//  gnf[g,n] = emb_{type(g,n)}
//  gef[g,n] = (sum_t cnt[g,n,t] * P_l[t]) / max(deg,1) + P_r[type(g,n)]
// Streaming 201 MB of writes -> nontemporal stores (no reuse, > L2).
// ---------------------------------------------------------------------------
__global__ __launch_bounds__(256)
void out_kernel(const int* __restrict__ nodes,     // (G, NODES)
                const int* __restrict__ cnt,       // (G, NN, 5)
                const float* __restrict__ node_emb,
                const float* __restrict__ graph_emb,
                const float* __restrict__ P_l,
                const float* __restrict__ P_r,
                float* __restrict__ gnf,           // (G, NN, H)
                float* __restrict__ gef)           // (G, NN, H)
{
    int tid = blockIdx.x * blockDim.x + threadIdx.x;   // G*NN*(H/4) threads
    int row = tid / (H_ / 4);                          // (g*NN + n)
    int j4  = tid % (H_ / 4);                          // float4 index in row
    int g = row >> 9;                                  // NN = 512
    int n = row & (NN_ - 1);

    int type = (n == 0) ? 0 : (nodes[g * NODES_ + n - 1] + 1);

    const int* c = cnt + (size_t)row * NTYPE;
    float c0 = (float)c[0], c1 = (float)c[1], c2 = (float)c[2],
          c3 = (float)c[3], c4 = (float)c[4];
    float deg = c0 + c1 + c2 + c3 + c4;
    float inv = 1.0f / fmaxf(deg, 1.0f);

    int h = j4 * 4;
    f32x4 p0 = *(const f32x4*)(P_l + 0 * H_ + h);
    f32x4 p1 = *(const f32x4*)(P_l + 1 * H_ + h);
    f32x4 p2 = *(const f32x4*)(P_l + 2 * H_ + h);
    f32x4 p3 = *(const f32x4*)(P_l + 3 * H_ + h);
    f32x4 p4 = *(const f32x4*)(P_l + 4 * H_ + h);
    f32x4 pr = *(const f32x4*)(P_r + (size_t)type * H_ + h);

    f32x4 o = (c0 * p0 + c1 * p1 + c2 * p2 + c3 * p3 + c4 * p4) * inv + pr;

    const float* emb = (type == 0) ? graph_emb : (node_emb + (size_t)(type - 1) * H_);
    f32x4 ev = *(const f32x4*)(emb + h);

    size_t off = (size_t)row * H_ + h;
    __builtin_nontemporal_store(ev, (f32x4*)(gnf + off));
    __builtin_nontemporal_store(o,  (f32x4*)(gef + off));
}

// ---------------------------------------------------------------------------
extern "C" void kernel_launch(void* const* d_in, const int* in_sizes, int n_in,
                              void* d_out, int out_size, void* d_ws, size_t ws_size,
                              hipStream_t stream)
{
    const int*   input_nodes = (const int*)d_in[0];   // (G, NODES) int32
    const int*   input_edges = (const int*)d_in[1];   // (G, 2, E)  int32
    const float* node_emb    = (const float*)d_in[2]; // (4, H)
    const float* graph_emb   = (const float*)d_in[3]; // (1, H)
    const float* W_l         = (const float*)d_in[4]; // (H, H)
    const float* b_l         = (const float*)d_in[5]; // (H,)
    const float* W_r         = (const float*)d_in[6]; // (H, H)

    float* gnf = (float*)d_out;                        // output 0: (G, NN, H)
    float* gef = gnf + (size_t)G_ * NN_ * H_;          // output 1: (G, NN, H)

    int*   cnt = (int*)d_ws;                                    // G*NN*5 ints = 2.62 MB
    size_t cnt_bytes = (size_t)G_ * NN_ * NTYPE * sizeof(int);
    float* P_l = (float*)((char*)d_ws + cnt_bytes);             // 5*H floats
    float* P_r = P_l + NTYPE * H_;                              // 5*H floats

    // Fused count+proj: 64 count blocks + 960 proj blocks, 512 threads each.
    prep_kernel<<<G_ + (2 * NTYPE * H_) / 8, 512, 0, stream>>>(
        input_edges, input_nodes, node_emb, graph_emb, W_l, b_l, W_r,
        cnt, P_l, P_r);

    // G*NN*(H/4) = 6291456 = 24576 * 256
    out_kernel<<<(G_ * NN_ * (H_ / 4)) / 256, 256, 0, stream>>>(
        input_nodes, cnt, node_emb, graph_emb, P_l, P_r, gnf, gef);
}